// Round 5
// baseline (240.986 us; speedup 1.0000x reference)
//
#include <hip/hip_runtime.h>

// emb lookup -> RNN tanh(xp_t + h @ W_hh^T) over S=128 -> 5-class head.
// B=4096, S=128, D=256, VOCAB=50000. Floats f32, x int32, out f32.
//
// Phase 0: P[v] = bf16(emb[v] @ W_ih^T + b_ih + b_hh)  (project the 50k TABLE, not 524k
//          tokens). 768 blocks, software-pipelined staging (raw float4 prefetch).
// Phase 1: 256 blocks x 16 rows x 512 thr (8 waves = 2/SIMD; 16 waves would double the
//          LDS A-read traffic to ~1540 cyc/step — 8 is the sweet spot). W_hh in VGPRs;
//          h/xp double-buffered in LDS; t-loop unrolled x2 with PRECOMPUTED LDS pointers
//          so all in-loop LDS ops are reg+immediate (round-4 recomputed addresses every
//          step -> VALU-issue-bound at 1100 cyc/SIMD/step); gathers prefetched 2 steps.

typedef __attribute__((ext_vector_type(8))) short bf16x8;   // 8 bf16 = 4 VGPRs
typedef __attribute__((ext_vector_type(4))) float f32x4;    // MFMA 16x16 accumulator

#define LDS_STRIDE 264   // 256 + 8 pad; 16B-aligned rows, dword stride 132 == 4 (mod 32)
#define VOCAB 50000
#define NBLK_EMB 768

__device__ __align__(256) unsigned short g_P[VOCAB * 256];  // 25.6 MB projected table

static __device__ __forceinline__ float bf2f(unsigned short u) {
    union { unsigned int i; float f; } v; v.i = ((unsigned int)u) << 16; return v.f;
}
static __device__ __forceinline__ unsigned short f2bf(float f) {
    union { float f; unsigned int i; } v; v.f = f;
    unsigned int r = v.i + 0x7FFFu + ((v.i >> 16) & 1u);   // RNE
    return (unsigned short)(r >> 16);
}
static __device__ __forceinline__ bf16x8 cvt8(float4 a, float4 b) {
    bf16x8 r;
    r[0] = (short)f2bf(a.x); r[1] = (short)f2bf(a.y);
    r[2] = (short)f2bf(a.z); r[3] = (short)f2bf(a.w);
    r[4] = (short)f2bf(b.x); r[5] = (short)f2bf(b.y);
    r[6] = (short)f2bf(b.z); r[7] = (short)f2bf(b.w);
    return r;
}
static __device__ __forceinline__ bf16x8 load8_bf(const float* __restrict__ p) {
    return cvt8(((const float4*)p)[0], ((const float4*)p)[1]);
}
// tanh(x) = 1 - 2/(e^{2x}+1); clamp keeps exp finite (tanh(+-8)==+-1 to 2e-7)
static __device__ __forceinline__ float fast_tanh(float x) {
    x = fminf(8.f, fmaxf(-8.f, x));
    float e = __expf(2.f * x);
    return 1.f - 2.f * __builtin_amdgcn_rcpf(e + 1.f);
}

// ---------------- Phase 0: P = bf16(emb @ W_ih^T + (b_ih + b_hh)) ----------------
__global__ __launch_bounds__(256)
void emb_proj_kernel(const float* __restrict__ emb,
                     const float* __restrict__ W_ih,
                     const float* __restrict__ b_ih,
                     const float* __restrict__ b_hh)
{
    __shared__ __align__(16) unsigned short tin [16 * LDS_STRIDE];
    __shared__ __align__(16) unsigned short tout[16 * LDS_STRIDE];
    const int tid  = threadIdx.x;
    const int lane = tid & 63;
    const int wid  = tid >> 6;          // 4 waves
    const int n0   = wid * 64;
    const int row  = tid >> 4, seg = tid & 15;

    // W_ih -> bf16 B-fragments, once per block: n = lane&15, k = quad*8 + kt*32 + j
    bf16x8 wf[4][8];
    float  bias[4];
    #pragma unroll
    for (int nt = 0; nt < 4; ++nt) {
        int n = n0 + nt * 16 + (lane & 15);
        bias[nt] = b_ih[n] + b_hh[n];
        #pragma unroll
        for (int kt = 0; kt < 8; ++kt)
            wf[nt][kt] = load8_bf(W_ih + n * 256 + (lane >> 4) * 8 + kt * 32);
    }

    int tile = blockIdx.x;
    // prefetch first tile's stage (raw f32; convert at use so loads stay in flight)
    float4 a0, a1, a2, a3;
    {
        const float4* s = (const float4*)(emb + ((size_t)tile * 16 + row) * 256 + seg * 16);
        a0 = s[0]; a1 = s[1]; a2 = s[2]; a3 = s[3];
    }

    for (; tile < 3125; tile += NBLK_EMB) {
        // convert + write staged regs to tin (prev iter's tin reads finished at barrier 2)
        *(bf16x8*)(&tin[row * LDS_STRIDE + seg * 16])     = cvt8(a0, a1);
        *(bf16x8*)(&tin[row * LDS_STRIDE + seg * 16 + 8]) = cvt8(a2, a3);
        // issue next tile's loads now; they fly across the MFMA phase
        int tn = tile + NBLK_EMB;
        if (tn < 3125) {
            const float4* s = (const float4*)(emb + ((size_t)tn * 16 + row) * 256 + seg * 16);
            a0 = s[0]; a1 = s[1]; a2 = s[2]; a3 = s[3];
        }
        __syncthreads();   // B1: tin visible

        f32x4 acc[4];
        #pragma unroll
        for (int nt = 0; nt < 4; ++nt) acc[nt] = (f32x4){0.f, 0.f, 0.f, 0.f};
        #pragma unroll
        for (int kt = 0; kt < 8; ++kt) {
            bf16x8 a = *(bf16x8*)(&tin[(lane & 15) * LDS_STRIDE + (lane >> 4) * 8 + kt * 32]);
            #pragma unroll
            for (int nt = 0; nt < 4; ++nt)
                acc[nt] = __builtin_amdgcn_mfma_f32_16x16x32_bf16(a, wf[nt][kt], acc[nt], 0, 0, 0);
        }
        // C/D: col = lane&15, row = quad*4 + r
        #pragma unroll
        for (int nt = 0; nt < 4; ++nt) {
            int n = n0 + nt * 16 + (lane & 15);
            #pragma unroll
            for (int r = 0; r < 4; ++r)
                tout[((lane >> 4) * 4 + r) * LDS_STRIDE + n] = f2bf(acc[nt][r] + bias[nt]);
        }
        __syncthreads();   // B2: tout complete, tin A-reads complete
        {
            uint4 o0 = *(uint4*)(&tout[row * LDS_STRIDE + seg * 16]);
            uint4 o1 = *(uint4*)(&tout[row * LDS_STRIDE + seg * 16 + 8]);
            uint4* dst = (uint4*)(g_P + ((size_t)tile * 16 + row) * 256 + seg * 16);
            dst[0] = o0; dst[1] = o1;
        }
    }
}

// ---------------- Phase 1: recurrence + classifier ----------------
__global__ __launch_bounds__(512, 1)
void rnn_kernel(const int* __restrict__ x,
                const float* __restrict__ W_hh,
                const float* __restrict__ W_cls,
                const float* __restrict__ b_cls,
                float* __restrict__ out)
{
    __shared__ __align__(16) unsigned short h_lds [2][16 * LDS_STRIDE];
    __shared__ __align__(16) unsigned short xp_lds[2][16 * LDS_STRIDE];
    __shared__ __align__(16) int tok_lds[16 * 128];
    __shared__ __align__(16) float wcls_lds[5 * 256];
    __shared__ float bcls_lds[5];

    const int tid   = threadIdx.x;
    const int lane  = tid & 63;
    const int wid   = tid >> 6;          // 8 waves
    const int b0    = blockIdx.x * 16;   // 256 * 16 == 4096
    const int n0    = wid * 32;          // wave's 32-col slice (2 x 16)
    const int grow  = tid >> 5;          // gather: row 0..15
    const int gseg  = tid & 31;          // gather: 8-bf16 (16B) segment

    // W_hh -> bf16 B-fragments (2 nt x 8 kt), VGPR-resident all 128 steps
    bf16x8 wf[2][8];
    #pragma unroll
    for (int nt = 0; nt < 2; ++nt) {
        int n = n0 + nt * 16 + (lane & 15);
        #pragma unroll
        for (int kt = 0; kt < 8; ++kt)
            wf[nt][kt] = load8_bf(W_hh + n * 256 + (lane >> 4) * 8 + kt * 32);
    }

    ((int4*)tok_lds)[tid] = ((const int4*)(x + (size_t)b0 * 128))[tid];
    if (tid < 320) ((float4*)wcls_lds)[tid] = ((const float4*)W_cls)[tid];
    if (tid < 5)   bcls_lds[tid] = b_cls[tid];
    for (int i = tid; i < 16 * LDS_STRIDE / 2; i += 512) ((unsigned int*)h_lds[0])[i] = 0;

    // prefetch xp(t=0) into LDS, xp(t=1) into regs
    float4 p_cur;
    {
        int t0 = x[(size_t)(b0 + grow) * 128 + 0];
        t0 = min(max(t0, 0), VOCAB - 1);
        *(float4*)(&xp_lds[0][grow * LDS_STRIDE + gseg * 8]) =
            *(const float4*)(g_P + (size_t)t0 * 256 + gseg * 8);
        int t1 = x[(size_t)(b0 + grow) * 128 + 1];
        t1 = min(max(t1, 0), VOCAB - 1);
        p_cur = *(const float4*)(g_P + (size_t)t1 * 256 + gseg * 8);
    }
    __syncthreads();

    // precomputed LDS base pointers — in-loop LDS ops are reg + immediate offset only
    const int colA = (lane & 15) * LDS_STRIDE + (lane >> 4) * 8;   // A-frag base
    const int colC = ((lane >> 4) * 4) * LDS_STRIDE + n0 + (lane & 15);  // C/epilogue base
    const unsigned short* hA0 = &h_lds[0][colA];
    const unsigned short* hA1 = &h_lds[1][colA];
    const unsigned short* xR0 = &xp_lds[0][colC];
    const unsigned short* xR1 = &xp_lds[1][colC];
    unsigned short* hW0 = &h_lds[0][colC];
    unsigned short* hW1 = &h_lds[1][colC];
    unsigned short* gw0 = &xp_lds[0][grow * LDS_STRIDE + gseg * 8];
    unsigned short* gw1 = &xp_lds[1][grow * LDS_STRIDE + gseg * 8];

    auto step = [&](const unsigned short* hA, const unsigned short* xR,
                    unsigned short* hW, unsigned short* gw, int t) {
        // prefetch gather for t+2 (lands while MFMA+tanh run; written next step)
        float4 p_nxt;
        if (t + 2 < 128) {
            int tok = tok_lds[grow * 128 + t + 2];
            tok = min(max(tok, 0), VOCAB - 1);
            p_nxt = *(const float4*)(g_P + (size_t)tok * 256 + gseg * 8);
        }
        // xp reads (8 x u16, reg+imm)
        float xp[2][4];
        #pragma unroll
        for (int nt = 0; nt < 2; ++nt)
            #pragma unroll
            for (int r = 0; r < 4; ++r)
                xp[nt][r] = bf2f(xR[r * LDS_STRIDE + nt * 16]);
        f32x4 acc0 = (f32x4){0.f, 0.f, 0.f, 0.f};
        f32x4 acc1 = (f32x4){0.f, 0.f, 0.f, 0.f};
        #pragma unroll
        for (int kt = 0; kt < 8; ++kt) {
            bf16x8 a = *(const bf16x8*)(hA + kt * 32);
            acc0 = __builtin_amdgcn_mfma_f32_16x16x32_bf16(a, wf[0][kt], acc0, 0, 0, 0);
            acc1 = __builtin_amdgcn_mfma_f32_16x16x32_bf16(a, wf[1][kt], acc1, 0, 0, 0);
        }
        #pragma unroll
        for (int r = 0; r < 4; ++r) {
            hW[r * LDS_STRIDE]      = f2bf(fast_tanh(acc0[r] + xp[0][r]));
            hW[r * LDS_STRIDE + 16] = f2bf(fast_tanh(acc1[r] + xp[1][r]));
        }
        if (t + 1 < 128)
            *(float4*)gw = p_cur;    // xp for t+1 into the buffer being written
        p_cur = p_nxt;
    };

    #pragma unroll 1
    for (int t2 = 0; t2 < 64; ++t2) {
        step(hA0, xR0, hW1, gw1, 2 * t2);      // read buf0, write buf1
        __syncthreads();
        step(hA1, xR1, hW0, gw0, 2 * t2 + 1);  // read buf1, write buf0
        __syncthreads();
    }

    // final h (t=127 wrote buf0): out[b][c] = h . W_cls[c] + b_cls[c]
    if (tid < 80) {
        int row = tid / 5, c = tid % 5;
        float acc = bcls_lds[c];
        for (int k = 0; k < 256; ++k)
            acc += bf2f(h_lds[0][row * LDS_STRIDE + k]) * wcls_lds[c * 256 + k];
        out[(size_t)(b0 + row) * 5 + c] = acc;
    }
}

extern "C" void kernel_launch(void* const* d_in, const int* in_sizes, int n_in,
                              void* d_out, int out_size, void* d_ws, size_t ws_size,
                              hipStream_t stream)
{
    const int*   x     = (const int*)d_in[0];
    const float* emb   = (const float*)d_in[1];
    const float* W_ih  = (const float*)d_in[2];
    const float* W_hh  = (const float*)d_in[3];
    const float* b_ih  = (const float*)d_in[4];
    const float* b_hh  = (const float*)d_in[5];
    const float* W_cls = (const float*)d_in[6];
    const float* b_cls = (const float*)d_in[7];
    float*       out   = (float*)d_out;
    (void)d_ws; (void)ws_size;

    emb_proj_kernel<<<NBLK_EMB, 256, 0, stream>>>(emb, W_ih, b_ih, b_hh);
    rnn_kernel<<<256, 512, 0, stream>>>(x, W_hh, W_cls, b_cls, out);
}

// Round 6
// 226.087 us; speedup vs baseline: 1.0659x; 1.0659x over previous
//
#include <hip/hip_runtime.h>

// emb lookup -> RNN tanh(xp_t + h @ W_hh^T) over S=128 -> 5-class head.
// B=4096, S=128, D=256, VOCAB=50000. Floats f32, x int32, out f32.
//
// Phase 0: P[v] = bf16(emb[v] @ W_ih^T + b_ih + b_hh) — project the 50k TABLE.
// Phase 1: 256 blocks x 16 rows x 512 thr (8 waves). W_hh bf16 B-frags in VGPRs.
//   R6: xp never touches LDS — gathered straight into MFMA C-layout registers and fed
//   as the MFMA C operand (acc init). h stored in a granule-XOR-swizzled LDS layout
//   (stride 256, granule g^row): h-writes conflict-free (R5 had 4-way conflicts,
//   8.8M cyc/dispatch). All LDS addrs precomputed; double-buffer via +8192 imm.

typedef __attribute__((ext_vector_type(8))) short bf16x8;   // 8 bf16 = 4 VGPRs
typedef __attribute__((ext_vector_type(4))) float f32x4;    // MFMA 16x16 accumulator

#define VOCAB 50000
#define NBLK_EMB 256
#define LDS_STRIDE 264   // emb kernel staging only

__device__ __align__(256) unsigned short g_P[VOCAB * 256];  // 25.6 MB projected table

static __device__ __forceinline__ float bf2f(unsigned short u) {
    union { unsigned int i; float f; } v; v.i = ((unsigned int)u) << 16; return v.f;
}
static __device__ __forceinline__ float bfbits2f(unsigned int zext_u16) {
    union { unsigned int i; float f; } v; v.i = zext_u16 << 16; return v.f;
}
static __device__ __forceinline__ unsigned short f2bf_rne(float f) {
    union { float f; unsigned int i; } v; v.f = f;
    unsigned int r = v.i + 0x7FFFu + ((v.i >> 16) & 1u);
    return (unsigned short)(r >> 16);
}
static __device__ __forceinline__ unsigned short f2bf_fast(float f) {   // round-half-up
    union { float f; unsigned int i; } v; v.f = f;
    return (unsigned short)((v.i + 0x8000u) >> 16);
}
static __device__ __forceinline__ bf16x8 cvt8(float4 a, float4 b) {
    bf16x8 r;
    r[0] = (short)f2bf_rne(a.x); r[1] = (short)f2bf_rne(a.y);
    r[2] = (short)f2bf_rne(a.z); r[3] = (short)f2bf_rne(a.w);
    r[4] = (short)f2bf_rne(b.x); r[5] = (short)f2bf_rne(b.y);
    r[6] = (short)f2bf_rne(b.z); r[7] = (short)f2bf_rne(b.w);
    return r;
}
static __device__ __forceinline__ bf16x8 load8_bf(const float* __restrict__ p) {
    return cvt8(((const float4*)p)[0], ((const float4*)p)[1]);
}
// tanh(x) = 1 - 2/(e^{2x}+1); med3 clamp keeps exp finite
static __device__ __forceinline__ float fast_tanh(float x) {
    x = __builtin_amdgcn_fmed3f(x, -8.f, 8.f);
    float e = __expf(2.f * x);
    return __builtin_fmaf(-2.f, __builtin_amdgcn_rcpf(e + 1.f), 1.f);
}

// ---------------- Phase 0: P = bf16(emb @ W_ih^T + (b_ih + b_hh)) ----------------
__global__ __launch_bounds__(256)
void emb_proj_kernel(const float* __restrict__ emb,
                     const float* __restrict__ W_ih,
                     const float* __restrict__ b_ih,
                     const float* __restrict__ b_hh)
{
    __shared__ __align__(16) unsigned short tin [16 * LDS_STRIDE];
    __shared__ __align__(16) unsigned short tout[16 * LDS_STRIDE];
    const int tid  = threadIdx.x;
    const int lane = tid & 63;
    const int wid  = tid >> 6;
    const int n0   = wid * 64;
    const int row  = tid >> 4, seg = tid & 15;

    bf16x8 wf[4][8];
    float  bias[4];
    #pragma unroll
    for (int nt = 0; nt < 4; ++nt) {
        int n = n0 + nt * 16 + (lane & 15);
        bias[nt] = b_ih[n] + b_hh[n];
        #pragma unroll
        for (int kt = 0; kt < 8; ++kt)
            wf[nt][kt] = load8_bf(W_ih + n * 256 + (lane >> 4) * 8 + kt * 32);
    }

    int tile = blockIdx.x;
    float4 a0, a1, a2, a3;
    {
        const float4* s = (const float4*)(emb + ((size_t)tile * 16 + row) * 256 + seg * 16);
        a0 = s[0]; a1 = s[1]; a2 = s[2]; a3 = s[3];
    }

    for (; tile < 3125; tile += NBLK_EMB) {
        *(bf16x8*)(&tin[row * LDS_STRIDE + seg * 16])     = cvt8(a0, a1);
        *(bf16x8*)(&tin[row * LDS_STRIDE + seg * 16 + 8]) = cvt8(a2, a3);
        int tn = tile + NBLK_EMB;
        if (tn < 3125) {
            const float4* s = (const float4*)(emb + ((size_t)tn * 16 + row) * 256 + seg * 16);
            a0 = s[0]; a1 = s[1]; a2 = s[2]; a3 = s[3];
        }
        __syncthreads();   // B1: tin visible

        f32x4 acc[4];
        #pragma unroll
        for (int nt = 0; nt < 4; ++nt) acc[nt] = (f32x4){0.f, 0.f, 0.f, 0.f};
        #pragma unroll
        for (int kt = 0; kt < 8; ++kt) {
            bf16x8 a = *(bf16x8*)(&tin[(lane & 15) * LDS_STRIDE + (lane >> 4) * 8 + kt * 32]);
            #pragma unroll
            for (int nt = 0; nt < 4; ++nt)
                acc[nt] = __builtin_amdgcn_mfma_f32_16x16x32_bf16(a, wf[nt][kt], acc[nt], 0, 0, 0);
        }
        #pragma unroll
        for (int nt = 0; nt < 4; ++nt) {
            int n = n0 + nt * 16 + (lane & 15);
            #pragma unroll
            for (int r = 0; r < 4; ++r)
                tout[((lane >> 4) * 4 + r) * LDS_STRIDE + n] = f2bf_rne(acc[nt][r] + bias[nt]);
        }
        __syncthreads();   // B2: tout complete, tin reads complete
        {
            uint4 o0 = *(uint4*)(&tout[row * LDS_STRIDE + seg * 16]);
            uint4 o1 = *(uint4*)(&tout[row * LDS_STRIDE + seg * 16 + 8]);
            uint4* dst = (uint4*)(g_P + ((size_t)tile * 16 + row) * 256 + seg * 16);
            dst[0] = o0; dst[1] = o1;
        }
    }
}

// ---------------- Phase 1: recurrence + classifier ----------------
// h LDS layout (per 8KB buffer): element (row m, col c) at byte
//   m*512 + (((c>>3) ^ m) << 4) + (c&7)*2      (granule-XOR swizzle, conflict-free writes)
__global__ __launch_bounds__(512, 2)
void rnn_kernel(const int* __restrict__ x,
                const float* __restrict__ W_hh,
                const float* __restrict__ W_cls,
                const float* __restrict__ b_cls,
                float* __restrict__ out)
{
    __shared__ __align__(16) unsigned short h_lds[2][16 * 256];  // 2 x 8 KB
    __shared__ __align__(16) int tok_t[128 * 16];                // [t][row]
    __shared__ __align__(16) float wcls_lds[5 * 256];
    __shared__ float bcls_lds[5];

    const int tid  = threadIdx.x;
    const int lane = tid & 63;
    const int wid  = tid >> 6;          // 8 waves
    const int b0   = blockIdx.x * 16;
    const int n0   = wid * 32;          // wave's 32-col slice
    const int l15  = lane & 15;
    const int quad = lane >> 4;

    // W_hh -> bf16 B-fragments, VGPR-resident
    bf16x8 wf[2][8];
    #pragma unroll
    for (int nt = 0; nt < 2; ++nt) {
        int n = n0 + nt * 16 + l15;
        #pragma unroll
        for (int kt = 0; kt < 8; ++kt)
            wf[nt][kt] = load8_bf(W_hh + n * 256 + quad * 8 + kt * 32);
    }

    // stage tokens transposed: tok_t[t*16 + row]
    {
        int row = tid & 15, tq = tid >> 4;   // tq 0..31
        int4 v = *(const int4*)(x + (size_t)(b0 + row) * 128 + tq * 4);
        tok_t[(tq * 4 + 0) * 16 + row] = v.x;
        tok_t[(tq * 4 + 1) * 16 + row] = v.y;
        tok_t[(tq * 4 + 2) * 16 + row] = v.z;
        tok_t[(tq * 4 + 3) * 16 + row] = v.w;
    }
    if (tid < 320) ((float4*)wcls_lds)[tid] = ((const float4*)W_cls)[tid];
    if (tid < 5)   bcls_lds[tid] = b_cls[tid];
    #pragma unroll
    for (int i = 0; i < 4; ++i) ((unsigned int*)h_lds[0])[tid + i * 512] = 0;

    // precomputed LDS byte offsets (loop-invariant; buf1 = +8192 imm)
    int aoff[8];
    #pragma unroll
    for (int kt = 0; kt < 8; ++kt)
        aoff[kt] = l15 * 512 + (((quad + 4 * kt) ^ l15) << 4);
    int woff[8];   // [nt*4 + r]
    #pragma unroll
    for (int nt = 0; nt < 2; ++nt)
        #pragma unroll
        for (int r = 0; r < 4; ++r) {
            int row = quad * 4 + r;
            int g   = (n0 >> 3) + nt * 2 + (l15 >> 3);
            woff[nt * 4 + r] = row * 512 + ((g ^ row) << 4) + (l15 & 7) * 2;
        }

    const unsigned int colByte = (unsigned int)(n0 + l15) * 2;   // within a g_P row

    // prologue: gather xp(t=0) -> gA, xp(t=1) -> gB (C-layout: row quad*4+r, col n0+nt*16+l15)
    unsigned int gA[8], gB[8];
    #pragma unroll
    for (int r = 0; r < 4; ++r) {
        const int* xr = x + (size_t)(b0 + quad * 4 + r) * 128;
        const unsigned short* p0 = g_P + (size_t)xr[0] * 256 + n0 + l15;
        const unsigned short* p1 = g_P + (size_t)xr[1] * 256 + n0 + l15;
        gA[r] = p0[0]; gA[4 + r] = p0[16];
        gB[r] = p1[0]; gB[4 + r] = p1[16];
    }
    __syncthreads();

    char* const h0 = (char*)&h_lds[0][0];

    auto step = [&](const char* hA, char* hW, unsigned int* g, int t) {
        // consume g as MFMA C operand (xp pre-added for free)
        f32x4 acc0 = { bfbits2f(g[0]), bfbits2f(g[1]), bfbits2f(g[2]), bfbits2f(g[3]) };
        f32x4 acc1 = { bfbits2f(g[4]), bfbits2f(g[5]), bfbits2f(g[6]), bfbits2f(g[7]) };
        // refill g for t+2 (in flight across 2 barriers)
        if (t + 2 < 128) {
            int4 tk = *(const int4*)&tok_t[(t + 2) * 16 + quad * 4];
            const unsigned short* r0 = (const unsigned short*)((const char*)g_P + ((unsigned int)tk.x * 512 + colByte));
            const unsigned short* r1 = (const unsigned short*)((const char*)g_P + ((unsigned int)tk.y * 512 + colByte));
            const unsigned short* r2 = (const unsigned short*)((const char*)g_P + ((unsigned int)tk.z * 512 + colByte));
            const unsigned short* r3 = (const unsigned short*)((const char*)g_P + ((unsigned int)tk.w * 512 + colByte));
            g[0] = r0[0]; g[4] = r0[16];
            g[1] = r1[0]; g[5] = r1[16];
            g[2] = r2[0]; g[6] = r2[16];
            g[3] = r3[0]; g[7] = r3[16];
        }
        #pragma unroll
        for (int kt = 0; kt < 8; ++kt) {
            bf16x8 a = *(const bf16x8*)(hA + aoff[kt]);
            acc0 = __builtin_amdgcn_mfma_f32_16x16x32_bf16(a, wf[0][kt], acc0, 0, 0, 0);
            acc1 = __builtin_amdgcn_mfma_f32_16x16x32_bf16(a, wf[1][kt], acc1, 0, 0, 0);
        }
        #pragma unroll
        for (int r = 0; r < 4; ++r) {
            *(unsigned short*)(hW + woff[r])     = f2bf_fast(fast_tanh(acc0[r]));
            *(unsigned short*)(hW + woff[4 + r]) = f2bf_fast(fast_tanh(acc1[r]));
        }
    };

    #pragma unroll 1
    for (int t2 = 0; t2 < 64; ++t2) {
        step(h0,        h0 + 8192, gA, 2 * t2);      // read buf0, write buf1
        __syncthreads();
        step(h0 + 8192, h0,        gB, 2 * t2 + 1);  // read buf1, write buf0
        __syncthreads();
    }

    // final h in buf0. Classifier: 4 threads per (row,c), shuffle-reduce.
    if (tid < 320) {
        int q = tid & 3, p = tid >> 2;
        int row = p / 5, c = p - row * 5;
        float acc = 0.f;
        #pragma unroll
        for (int kk = 0; kk < 64; ++kk) {
            int k = q * 64 + kk;
            int off = row * 512 + ((((k >> 3) ^ row)) << 4) + (k & 7) * 2;
            acc += bf2f(*(const unsigned short*)(h0 + off)) * wcls_lds[c * 256 + k];
        }
        acc += __shfl_xor(acc, 1);
        acc += __shfl_xor(acc, 2);
        if (q == 0) out[(size_t)(b0 + row) * 5 + c] = acc + bcls_lds[c];
    }
}

extern "C" void kernel_launch(void* const* d_in, const int* in_sizes, int n_in,
                              void* d_out, int out_size, void* d_ws, size_t ws_size,
                              hipStream_t stream)
{
    const int*   x     = (const int*)d_in[0];
    const float* emb   = (const float*)d_in[1];
    const float* W_ih  = (const float*)d_in[2];
    const float* W_hh  = (const float*)d_in[3];
    const float* b_ih  = (const float*)d_in[4];
    const float* b_hh  = (const float*)d_in[5];
    const float* W_cls = (const float*)d_in[6];
    const float* b_cls = (const float*)d_in[7];
    float*       out   = (float*)d_out;
    (void)d_ws; (void)ws_size;

    emb_proj_kernel<<<NBLK_EMB, 256, 0, stream>>>(emb, W_ih, b_ih, b_hh);
    rnn_kernel<<<256, 512, 0, stream>>>(x, W_hh, W_cls, b_cls, out);
}